// Round 15
// baseline (336.810 us; speedup 1.0000x reference)
//
#include <hip/hip_runtime.h>
#include <hip/hip_bf16.h>
#include <stdint.h>

// Problem constants
#define NPAIR 512      // B*C
#define LTOK  128      // L
#define DDIM  768      // D
#define HDIM  768      // H
#define K2    1536     // 2*D
#define MARGIN 0.4f    // bf16-sim uncertainty margin (~9 sigma of gap error)

typedef float f32x4 __attribute__((ext_vector_type(4)));
typedef short bf16x8 __attribute__((ext_vector_type(8)));

// XOR swizzle for [row][32-bf16] LDS tiles (64B rows)
static __device__ __forceinline__ int fsw(int row) {
    return (row ^ (row >> 2)) & 3;
}

static __device__ __forceinline__ unsigned short f2bf(float f) {
    union { float f; uint32_t u; } v; v.f = f;
    uint32_t u = v.u;
    u += 0x7FFF + ((u >> 16) & 1);   // RNE
    return (unsigned short)(u >> 16);
}

// HW packed conversion: v_cvt_pk_bf16_f32 (RNE)
static __device__ __forceinline__ uint2 pack4(f32x4 v) {
    __hip_bfloat162 lo = __float22bfloat162_rn(float2{v[0], v[1]});
    __hip_bfloat162 hi = __float22bfloat162_rn(float2{v[2], v[3]});
    uint2 r;
    r.x = *reinterpret_cast<unsigned*>(&lo);
    r.y = *reinterpret_cast<unsigned*>(&hi);
    return r;
}

static __device__ __forceinline__ uint4 pack8(f32x4 a, f32x4 b) {
    uint2 lo = pack4(a), hi = pack4(b);
    uint4 r; r.x = lo.x; r.y = lo.y; r.z = hi.x; r.w = hi.y;
    return r;
}

typedef const __attribute__((address_space(1))) void* gas_t;
typedef __attribute__((address_space(3))) void* las_t;
static __device__ __forceinline__ void gld16(const void* g, void* l) {
    __builtin_amdgcn_global_load_lds((gas_t)g, (las_t)l, 16, 0, 0);
}

// exact fp32 dot over 768 elems, whole wave participates; all lanes return sum
static __device__ __forceinline__ float wave_dot(const float* __restrict__ a,
                                                 const float* __restrict__ b,
                                                 int lane) {
    f32x4 s4 = {0.f, 0.f, 0.f, 0.f};
#pragma unroll
    for (int it = 0; it < 3; ++it) {
        int k = it * 256 + lane * 4;
        f32x4 av = *(const f32x4*)(a + k);
        f32x4 bv = *(const f32x4*)(b + k);
#pragma unroll
        for (int q = 0; q < 4; ++q) s4[q] = fmaf(av[q], bv[q], s4[q]);
    }
    float v = (s4[0] + s4[1]) + (s4[2] + s4[3]);
#pragma unroll
    for (int m = 1; m < 64; m <<= 1) v += __shfl_xor(v, m);
    return v;
}

// ---------------------------------------------------------------------------
// FUSED kernel: one block per pair, 512 threads / 8 waves.
// Phase 1: bf16-MFMA sim, 2-deep register prefetch (R13) + RAW BARRIERS:
//   barrier A = s_waitcnt lgkmcnt(0) + s_barrier (ds_write visibility only);
//   barrier B = plain s_barrier (LDS reads consumed via register waits).
//   -> prefetch loads and WB stores stay in flight ACROSS barriers (T4),
//   removing the per-step vmcnt(0) drain that serialized HBM latency.
// Phase 2: MLP GEMM (R10, unchanged; its __syncthreads drains are required
//   for gld16 visibility). First post-loop __syncthreads drains WB stores
//   before phase 2 reads Cbf/Ebf.
// ---------------------------------------------------------------------------
__global__ __launch_bounds__(512, 4) void fused_kernel(
        const float* __restrict__ inp,
        const unsigned short* __restrict__ W1T,
        const float* __restrict__ b1,
        const float* __restrict__ W2,
        const float* __restrict__ b2,
        unsigned short* __restrict__ Cbf, unsigned short* __restrict__ Ebf,
        float* __restrict__ out)
{
    const int p    = blockIdx.x;
    const int t    = threadIdx.x;       // 0..511
    const int wv   = t >> 6;            // 0..7
    const int lane = t & 63;
    const int s    = lane & 15, g = lane >> 4;

    const float* Cbase = inp + (size_t)(2 * p) * LTOK * DDIM;
    const float* Ebase = Cbase + (size_t)LTOK * DDIM;

    __shared__ char  pool[49152];       // phase-overlapped
    __shared__ int   am[128];
    __shared__ float dm[128];
    __shared__ float tok[128];

    // phase-1 views of the pool
    unsigned short (*Cl)[128][32] = (unsigned short (*)[128][32])pool;
    unsigned short (*El)[128][32] = (unsigned short (*)[128][32])(pool + 16384);
    unsigned short (*cand)[16]    = (unsigned short (*)[16])(pool + 32768);
    int*   ccnt = (int*)(pool + 36864);
    float* rm1  = (float*)(pool + 37376);
    int*   ri1  = (int*)(pool + 37888);

    if (t < 128) { ccnt[t] = 0; tok[t] = 0.f; }

    // ================= Phase 1: sim + argmax =================
    f32x4 acc1[8];                       // rows wv*16+g*4+r, cols j*16+s
#pragma unroll
    for (int j = 0; j < 8; j++) acc1[j] = (f32x4){0.f, 0.f, 0.f, 0.f};

    const int srow0 = t >> 3;            // 0..63
    const int srow1 = 64 + srow0;        // 64..127
    const int so8   = t & 7;             // 8-elem chunk within 64-k
    const int sh    = so8 >> 2;          // k-half
    const int sq    = so8 & 3;           // logical 16B slot within half
    const int qs0   = (sq ^ fsw(srow0)) * 8;
    const int qs1   = (sq ^ fsw(srow1)) * 8;

    f32x4 cA[4], eA[4], cB[4], eB[4];    // 2-deep in-flight load buffers

    auto ISSUE = [&](int kc, f32x4* cb2, f32x4* eb2) {
        const int k0 = kc * 64;
        const float* c0a = Cbase + (size_t)srow0 * DDIM + k0 + so8 * 8;
        const float* c1a = Cbase + (size_t)srow1 * DDIM + k0 + so8 * 8;
        const float* e0a = Ebase + (size_t)srow0 * DDIM + k0 + so8 * 8;
        const float* e1a = Ebase + (size_t)srow1 * DDIM + k0 + so8 * 8;
        cb2[0] = *(const f32x4*)c0a;  cb2[1] = *(const f32x4*)(c0a + 4);
        cb2[2] = *(const f32x4*)c1a;  cb2[3] = *(const f32x4*)(c1a + 4);
        eb2[0] = *(const f32x4*)e0a;  eb2[1] = *(const f32x4*)(e0a + 4);
        eb2[2] = *(const f32x4*)e1a;  eb2[3] = *(const f32x4*)(e1a + 4);
    };

    auto STEP = [&](int kc, f32x4* cb2, f32x4* eb2) {
        const int k0 = kc * 64;
        uint4 cw0 = pack8(cb2[0], cb2[1]);   // reg-dep waits on THIS buffer only
        uint4 cw1 = pack8(cb2[2], cb2[3]);
        uint4 ew0 = pack8(eb2[0], eb2[1]);
        uint4 ew1 = pack8(eb2[2], eb2[3]);
        *(uint4*)&Cl[sh][srow0][qs0] = cw0;
        *(uint4*)&Cl[sh][srow1][qs1] = cw1;
        *(uint4*)&El[sh][srow0][qs0] = ew0;
        *(uint4*)&El[sh][srow1][qs1] = ew1;
        // barrier A: ds_writes visible; do NOT drain vmcnt (loads/stores fly on)
        asm volatile("s_waitcnt lgkmcnt(0)" ::: "memory");
        __builtin_amdgcn_s_barrier();

        if (kc + 2 < 12) ISSUE(kc + 2, cb2, eb2);   // 2-deep prefetch
        {                                            // WB acks whenever (no drain)
            size_t o0 = ((size_t)p * LTOK + srow0) * DDIM + k0 + so8 * 8;
            size_t o1 = ((size_t)p * LTOK + srow1) * DDIM + k0 + so8 * 8;
            *(uint4*)(Cbf + o0) = cw0;
            *(uint4*)(Cbf + o1) = cw1;
            *(uint4*)(Ebf + o0) = ew0;
            *(uint4*)(Ebf + o1) = ew1;
        }

#pragma unroll
        for (int hh = 0; hh < 2; ++hh) {
            const int arow = wv * 16 + s;
            bf16x8 af = *(const bf16x8*)&Cl[hh][arow][(g ^ fsw(arow)) * 8];
            bf16x8 bfr[8];
#pragma unroll
            for (int j = 0; j < 8; ++j) {
                const int row = j * 16 + s;
                bfr[j] = *(const bf16x8*)&El[hh][row][(g ^ fsw(row)) * 8];
            }
#pragma unroll
            for (int j = 0; j < 8; ++j)
                acc1[j] = __builtin_amdgcn_mfma_f32_16x16x32_bf16(af, bfr[j], acc1[j], 0, 0, 0);
        }
        // barrier B: all waves' LDS reads consumed (reg waits before MFMA);
        // plain barrier, no vmcnt drain.
        asm volatile("" ::: "memory");
        __builtin_amdgcn_s_barrier();
    };

    ISSUE(0, cA, eA);
    ISSUE(1, cB, eB);
    for (int kc = 0; kc < 12; kc += 2) {
        STEP(kc,     cA, eA);
        STEP(kc + 1, cB, eB);
    }

    // top-2 per row; row = wv*16 + g*4 + r
#pragma unroll
    for (int r = 0; r < 4; ++r) {
        float m1 = acc1[0][r]; int i1 = s; float m2 = -1e30f;
#pragma unroll
        for (int j = 1; j < 8; ++j) {
            float v = acc1[j][r]; int c = j * 16 + s;
            if (v > m1 || (v == m1 && c < i1)) { m2 = m1; m1 = v; i1 = c; }
            else if (v > m2) m2 = v;
        }
#pragma unroll
        for (int msk = 1; msk < 16; msk <<= 1) {
            float o1 = __shfl_xor(m1, msk);
            int   oi = __shfl_xor(i1, msk);
            float o2 = __shfl_xor(m2, msk);
            bool take = (o1 > m1) || (o1 == m1 && oi < i1);
            float nm2 = take ? fmaxf(m1, o2) : fmaxf(m2, o1);
            if (take) { m1 = o1; i1 = oi; }
            m2 = nm2;
        }
        int row = wv * 16 + g * 4 + r;
        if (s == 0) { rm1[row] = m1; ri1[row] = i1; }
        float thr = m1 - MARGIN;
#pragma unroll
        for (int j = 0; j < 8; ++j) {
            float v = acc1[j][r]; int c = j * 16 + s;
            if (v >= thr && c != i1) {
                int idx = atomicAdd(&ccnt[row], 1);
                if (idx < 16) cand[row][idx] = (unsigned short)c;
            }
        }
    }
    __syncthreads();   // full drain: WB stores + prefetch leftovers complete here

    // phase B: per row, commit bf16 result or exact-fp32 recheck -> am/dm LDS
    for (int rr = 0; rr < 16; ++rr) {
        int row = wv + rr * 8;
        int cnt = ccnt[row];
        float m1 = rm1[row]; int i1 = ri1[row];
        if (cnt == 0) {
            if (lane == 0) { dm[row] = m1; am[row] = i1; }
            continue;
        }
        const float* cr = Cbase + (size_t)row * DDIM;
        float bv; int bc;
        if (cnt <= 16) {
            bv = wave_dot(cr, Ebase + (size_t)i1 * DDIM, lane); bc = i1;
            for (int q = 0; q < cnt; ++q) {
                int c = cand[row][q];
                float v = wave_dot(cr, Ebase + (size_t)c * DDIM, lane);
                if (v > bv || (v == bv && c < bc)) { bv = v; bc = c; }
            }
        } else {
            bv = -1e30f; bc = 0;
            for (int c = 0; c < 128; ++c) {
                float v = wave_dot(cr, Ebase + (size_t)c * DDIM, lane);
                if (v > bv || (v == bv && c < bc)) { bv = v; bc = c; }
            }
        }
        if (lane == 0) { dm[row] = bv; am[row] = bc; }
    }
    __syncthreads();    // am/dm ready; phase-1 pool dead -> reuse

    // ================= Phase 2: MLP GEMM (R10, verified) =================
    unsigned short (*Ald)[128][32] = (unsigned short (*)[128][32])pool;
    unsigned short (*Bld)[256][32] = (unsigned short (*)[256][32])(pool + 16384);

    const int wr  = wv >> 2, wcg = wv & 3;  // 2x4 wave grid: 64 rows x 64 cols
    const int rsub = lane >> 2;             // 0..15
    const int chk  = lane & 3;              // 16B chunk

    for (int cb = 0; cb < 3; ++cb) {
        f32x4 acc[4][4];
#pragma unroll
        for (int i = 0; i < 4; i++)
#pragma unroll
            for (int j = 0; j < 4; j++) acc[i][j] = (f32x4){0.f, 0.f, 0.f, 0.f};

        auto STAGE = [&](int buf, int kt) {
            const int k0   = kt * 32;
            const bool ctx = (kt < 24);
            const int kloc = ctx ? k0 : (k0 - DDIM);
            // B: 2 gld16 per wave (16 cols x 64B each)
#pragma unroll
            for (int n = 0; n < 2; ++n) {
                int r0  = (wv * 2 + n) * 16;
                int col = r0 + rsub;                  // 0..255
                int ck  = chk ^ fsw(col);             // pre-swizzled source chunk
                gld16(W1T + (size_t)(cb * 256 + col) * K2 + k0 + ck * 8,
                      &Bld[buf][r0][0]);
            }
            // A: 1 gld16 per wave (16 rows x 64B)
            {
                int r0 = wv * 16;
                int r  = r0 + rsub;
                int ck = chk ^ fsw(r);
                const unsigned short* base = ctx
                    ? (Cbf + ((size_t)p * LTOK + r) * DDIM)
                    : (Ebf + ((size_t)p * LTOK + am[r]) * DDIM);
                gld16(base + kloc + ck * 8, &Ald[buf][r0][0]);
            }
        };

        STAGE(0, 0);
        __syncthreads();
        int cur = 0;
        for (int kt = 0; kt < 48; ++kt) {
            if (kt < 47) STAGE(cur ^ 1, kt + 1);   // next tile flies under MFMA
            bf16x8 af[4], bfr[4];
#pragma unroll
            for (int i = 0; i < 4; ++i) {
                const int row = wr * 64 + i * 16 + s;
                af[i] = *(const bf16x8*)&Ald[cur][row][(g ^ fsw(row)) * 8];
            }
#pragma unroll
            for (int j = 0; j < 4; ++j) {
                const int brow = wcg * 64 + j * 16 + s;
                bfr[j] = *(const bf16x8*)&Bld[cur][brow][(g ^ fsw(brow)) * 8];
            }
#pragma unroll
            for (int i = 0; i < 4; ++i)
#pragma unroll
                for (int j = 0; j < 4; ++j)
                    acc[i][j] = __builtin_amdgcn_mfma_f32_16x16x32_bf16(af[i], bfr[j], acc[i][j], 0, 0, 0);
            __syncthreads();
            cur ^= 1;
        }

        // epilogue: relu(acc + b1) . W2, reduce cols, accumulate LDS tok
        float w2v[4], b1v[4];
#pragma unroll
        for (int j = 0; j < 4; j++) {
            int col = cb * 256 + wcg * 64 + j * 16 + s;
            w2v[j] = W2[col];
            b1v[j] = b1[col];
        }
        float ss[4][4];
#pragma unroll
        for (int i = 0; i < 4; i++)
#pragma unroll
            for (int r = 0; r < 4; r++) ss[i][r] = 0.f;
#pragma unroll
        for (int i = 0; i < 4; i++)
#pragma unroll
            for (int j = 0; j < 4; j++)
#pragma unroll
                for (int r = 0; r < 4; r++) {
                    float h = acc[i][j][r] + b1v[j];
                    h = h > 0.f ? h : 0.f;
                    ss[i][r] = fmaf(h, w2v[j], ss[i][r]);
                }
#pragma unroll
        for (int sft = 1; sft < 16; sft <<= 1)
#pragma unroll
            for (int i = 0; i < 4; i++)
#pragma unroll
                for (int r = 0; r < 4; r++) ss[i][r] += __shfl_xor(ss[i][r], sft);
        if (s == 0) {
#pragma unroll
            for (int i = 0; i < 4; i++)
#pragma unroll
                for (int r = 0; r < 4; r++)
                    atomicAdd(&tok[wr * 64 + i * 16 + g * 4 + r], ss[i][r]);
        }
    }
    __syncthreads();

    // final: masked row sums -> out[p] (scores), out[512+p] (dot_scores)
    if (wv == 0) {
        float b2v = b2[0];
        float sc = 0.f, dd = 0.f;
#pragma unroll
        for (int rr = 0; rr < 2; ++rr) {
            int row = lane + rr * 64;
            float c0 = Cbase[(size_t)row * DDIM];
            float mk = (c0 != 0.f) ? 1.f : 0.f;
            sc += mk * (tok[row] + b2v);
            dd += mk * dm[row];
        }
#pragma unroll
        for (int m = 1; m < 64; m <<= 1) {
            sc += __shfl_xor(sc, m);
            dd += __shfl_xor(dd, m);
        }
        if (lane == 0) { out[p] = sc; out[NPAIR + p] = dd; }
    }
}

// ---------------------------------------------------------------------------
// Kernel 2: W1 [1536,768] fp32 -> W1T [768][1536] bf16 (coalesced writes)
// ---------------------------------------------------------------------------
__global__ __launch_bounds__(256) void w1t_kernel(
        const float* __restrict__ W1, unsigned short* __restrict__ W1T)
{
    int idx = blockIdx.x * 256 + threadIdx.x;
    if (idx >= HDIM * K2 / 8) return;
    int c  = idx / (K2 / 8);
    int k0 = (idx % (K2 / 8)) * 8;
    unsigned short v[8];
#pragma unroll
    for (int q = 0; q < 8; q++) v[q] = f2bf(W1[(size_t)(k0 + q) * HDIM + c]);
    *(uint4*)(W1T + (size_t)c * K2 + k0) = *(const uint4*)v;
}

// ---------------------------------------------------------------------------
// Fallback kernels (ws too small): fp32 sim + fused-gather MLP + atomics
// ---------------------------------------------------------------------------
__global__ __launch_bounds__(256) void sim_fp32_kernel(
        const float* __restrict__ inp,
        float* __restrict__ dotmax, int* __restrict__ argmax)
{
    const int p  = blockIdx.x;
    const int t  = threadIdx.x;
    const int tx = t & 15, ty = t >> 4;
    const float* Cbase = inp + (size_t)(2 * p) * LTOK * DDIM;
    const float* Ebase = Cbase + (size_t)LTOK * DDIM;

    __shared__ float Ct[128][36];
    __shared__ float Et[128][36];

    float acc[8][8];
#pragma unroll
    for (int i = 0; i < 8; i++)
#pragma unroll
        for (int j = 0; j < 8; j++) acc[i][j] = 0.f;

    for (int kc = 0; kc < 24; ++kc) {
        const int k0 = kc * 32;
#pragma unroll
        for (int q = 0; q < 4; ++q) {
            int f = q * 256 + t;
            int row = f >> 3, c4 = f & 7;
            *(f32x4*)&Ct[row][c4 * 4] = *(const f32x4*)(Cbase + (size_t)row * DDIM + k0 + c4 * 4);
            *(f32x4*)&Et[row][c4 * 4] = *(const f32x4*)(Ebase + (size_t)row * DDIM + k0 + c4 * 4);
        }
        __syncthreads();
#pragma unroll
        for (int kk4 = 0; kk4 < 8; ++kk4) {
            f32x4 cr[8], er[8];
#pragma unroll
            for (int i = 0; i < 8; i++) cr[i] = *(const f32x4*)&Ct[ty + 16 * i][kk4 * 4];
#pragma unroll
            for (int j = 0; j < 8; j++) er[j] = *(const f32x4*)&Et[tx + 16 * j][kk4 * 4];
#pragma unroll
            for (int kk = 0; kk < 4; kk++)
#pragma unroll
                for (int i = 0; i < 8; i++)
#pragma unroll
                    for (int j = 0; j < 8; j++)
                        acc[i][j] = fmaf(cr[i][kk], er[j][kk], acc[i][j]);
        }
        __syncthreads();
    }
#pragma unroll
    for (int i = 0; i < 8; i++) {
        float m = acc[i][0]; int mi = tx;
#pragma unroll
        for (int j = 1; j < 8; j++) {
            int c = tx + 16 * j;
            float v = acc[i][j];
            if (v > m || (v == m && c < mi)) { m = v; mi = c; }
        }
#pragma unroll
        for (int sft = 1; sft < 16; sft <<= 1) {
            float vo = __shfl_xor(m, sft);
            int   io = __shfl_xor(mi, sft);
            if (vo > m || (vo == m && io < mi)) { m = vo; mi = io; }
        }
        if (tx == 0) {
            int r = ty + 16 * i;
            dotmax[(size_t)p * LTOK + r] = m;
            argmax[(size_t)p * LTOK + r] = mi;
        }
    }
}

__global__ __launch_bounds__(256, 2) void mlp_kernel(
        const float* __restrict__ inp,
        const unsigned short* __restrict__ W1T,
        const float* __restrict__ b1,
        const float* __restrict__ W2,
        const int* __restrict__ argmax,
        float* __restrict__ tokscore)
{
    const int tile = blockIdx.x;
    const int cb   = blockIdx.y;
    const int t    = threadIdx.x;
    const int wv   = t >> 6;
    const int lane = t & 63;
    const int s    = lane & 15, g = lane >> 4;

    __shared__ unsigned short At[64][32];
    __shared__ unsigned short Bt[384][32];
    __shared__ int am[64];

    if (t < 64) am[t] = argmax[tile * 64 + t];
    __syncthreads();

    f32x4 acc[4][6];
#pragma unroll
    for (int i = 0; i < 4; i++)
#pragma unroll
        for (int j = 0; j < 6; j++) acc[i][j] = (f32x4){0.f, 0.f, 0.f, 0.f};

    for (int kc = 0; kc < 48; ++kc) {
        const int k0  = kc * 32;
        const int sel = (kc >= 24) ? 1 : 0;
        const int kloc = k0 - sel * DDIM;
#pragma unroll
        for (int q = 0; q < 2; ++q) {
            int f = q * 256 + t;
            int row = f >> 3, c4 = f & 7;
            int token = tile * 64 + row;
            int pp2 = token >> 7;
            int lsel = sel ? am[row] : (token & 127);
            const float* src = inp + ((size_t)(2 * pp2 + sel) * LTOK + lsel) * DDIM + kloc + c4 * 4;
            f32x4 v = *(const f32x4*)src;
            uint2 pk = pack4(v);
            *(uint2*)&At[row][c4 * 4] = pk;
        }
#pragma unroll
        for (int q = 0; q < 6; ++q) {
            int f = q * 256 + t;
            int colr = f >> 2, q8 = f & 3;
            const unsigned short* src = W1T + (size_t)(cb * 384 + colr) * K2 + k0 + q8 * 8;
            *(uint4*)&Bt[colr][q8 * 8] = *(const uint4*)src;
        }
        __syncthreads();

        bf16x8 af[4], bfr[6];
#pragma unroll
        for (int i = 0; i < 4; i++) af[i]  = *(const bf16x8*)&At[i * 16 + s][g * 8];
#pragma unroll
        for (int j = 0; j < 6; j++) bfr[j] = *(const bf16x8*)&Bt[wv * 96 + j * 16 + s][g * 8];
#pragma unroll
        for (int i = 0; i < 4; i++)
#pragma unroll
            for (int j = 0; j < 6; j++)
                acc[i][j] = __builtin_amdgcn_mfma_f32_16x16x32_bf16(af[i], bfr[j], acc[i][j], 0, 0, 0);
        __syncthreads();
    }

    float w2v[6], b1v[6];
#pragma unroll
    for (int j = 0; j < 6; j++) {
        int col = cb * 384 + wv * 96 + j * 16 + s;
        w2v[j] = W2[col];
        b1v[j] = b1[col];
    }
    float ssum[4][4];
#pragma unroll
    for (int i = 0; i < 4; i++)
#pragma unroll
        for (int r = 0; r < 4; r++) ssum[i][r] = 0.f;
#pragma unroll
    for (int i = 0; i < 4; i++)
#pragma unroll
        for (int j = 0; j < 6; j++)
#pragma unroll
            for (int r = 0; r < 4; r++) {
                float hh = acc[i][j][r] + b1v[j];
                hh = hh > 0.f ? hh : 0.f;
                ssum[i][r] = fmaf(hh, w2v[j], ssum[i][r]);
            }
#pragma unroll
    for (int sft = 1; sft < 16; sft <<= 1)
#pragma unroll
        for (int i = 0; i < 4; i++)
#pragma unroll
            for (int r = 0; r < 4; r++) ssum[i][r] += __shfl_xor(ssum[i][r], sft);
    if (s == 0) {
#pragma unroll
        for (int i = 0; i < 4; i++)
#pragma unroll
            for (int r = 0; r < 4; r++)
                atomicAdd(&tokscore[tile * 64 + i * 16 + g * 4 + r], ssum[i][r]);
    }
}

__global__ __launch_bounds__(128) void reduce_kernel(
        const float* __restrict__ inp,
        const float* __restrict__ tokscore,
        const float* __restrict__ dotmax,
        const float* __restrict__ b2,
        float* __restrict__ out)
{
    int p = blockIdx.x;
    int l = threadIdx.x;
    float c0  = inp[((size_t)(2 * p) * LTOK + l) * DDIM];
    float msk = (c0 != 0.0f) ? 1.f : 0.f;
    float sc  = (tokscore[p * LTOK + l] + b2[0]) * msk;
    float dmv = dotmax[p * LTOK + l] * msk;
#pragma unroll
    for (int sh = 1; sh < 64; sh <<= 1) {
        sc  += __shfl_xor(sc, sh);
        dmv += __shfl_xor(dmv, sh);
    }
    __shared__ float tmp[4];
    if ((l & 63) == 0) { tmp[(l >> 6) * 2] = sc; tmp[(l >> 6) * 2 + 1] = dmv; }
    __syncthreads();
    if (l == 0) {
        out[p]          = tmp[0] + tmp[2];
        out[NPAIR + p]  = tmp[1] + tmp[3];
    }
}

extern "C" void kernel_launch(void* const* d_in, const int* in_sizes, int n_in,
                              void* d_out, int out_size, void* d_ws, size_t ws_size,
                              hipStream_t stream)
{
    const float* inp = (const float*)d_in[0];
    const float* W1  = (const float*)d_in[1];
    const float* b1  = (const float*)d_in[2];
    const float* W2  = (const float*)d_in[3];
    const float* b2  = (const float*)d_in[4];
    float* out = (float*)d_out;

    char* ws = (char*)d_ws;
    unsigned short* W1T   = (unsigned short*)ws;                 // 2,359,296 B
    float*          dotmx = (float*)(ws + 2359296);              // fallback
    int*            amax  = (int*)(ws + 2359296 + 262144);       // fallback
    float*          toksc = (float*)(ws + 2359296 + 2*262144);   // fallback
    unsigned short* Cbf   = (unsigned short*)(ws + 2359296 + 3*262144);
    unsigned short* Ebf   = Cbf + (size_t)NPAIR * LTOK * DDIM;   // +100,663,296 B each
    const size_t NEED = 2359296ull + 3ull*262144ull + 2ull*100663296ull;

    const bool big = ws_size >= NEED;

    w1t_kernel<<<(HDIM * K2 / 8 + 255) / 256, 256, 0, stream>>>(W1, W1T);
    if (big) {
        fused_kernel<<<NPAIR, 512, 0, stream>>>(inp, W1T, b1, W2, b2, Cbf, Ebf, out);
    } else {
        hipMemsetAsync(toksc, 0, 65536 * sizeof(float), stream);
        sim_fp32_kernel<<<NPAIR, 256, 0, stream>>>(inp, dotmx, amax);
        mlp_kernel<<<dim3(1024, 2), 256, 0, stream>>>(inp, W1T, b1, W2, amax, toksc);
        reduce_kernel<<<NPAIR, 128, 0, stream>>>(inp, toksc, dotmx, b2, out);
    }
}

// Round 16
// 303.610 us; speedup vs baseline: 1.1094x; 1.1094x over previous
//
#include <hip/hip_runtime.h>
#include <hip/hip_bf16.h>
#include <stdint.h>

// Problem constants
#define NPAIR 512      // B*C
#define LTOK  128      // L
#define DDIM  768      // D
#define HDIM  768      // H
#define K2    1536     // 2*D
#define MARGIN 0.4f    // bf16-sim uncertainty margin (~9 sigma of gap error)

typedef float f32x4 __attribute__((ext_vector_type(4)));
typedef short bf16x8 __attribute__((ext_vector_type(8)));

// XOR swizzle for [row][32-bf16] LDS tiles (64B rows)
static __device__ __forceinline__ int fsw(int row) {
    return (row ^ (row >> 2)) & 3;
}

static __device__ __forceinline__ unsigned short f2bf(float f) {
    union { float f; uint32_t u; } v; v.f = f;
    uint32_t u = v.u;
    u += 0x7FFF + ((u >> 16) & 1);   // RNE
    return (unsigned short)(u >> 16);
}

// HW packed conversion: v_cvt_pk_bf16_f32 (RNE)
static __device__ __forceinline__ uint2 pack4(f32x4 v) {
    __hip_bfloat162 lo = __float22bfloat162_rn(float2{v[0], v[1]});
    __hip_bfloat162 hi = __float22bfloat162_rn(float2{v[2], v[3]});
    uint2 r;
    r.x = *reinterpret_cast<unsigned*>(&lo);
    r.y = *reinterpret_cast<unsigned*>(&hi);
    return r;
}

static __device__ __forceinline__ uint4 pack8(f32x4 a, f32x4 b) {
    uint2 lo = pack4(a), hi = pack4(b);
    uint4 r; r.x = lo.x; r.y = lo.y; r.z = hi.x; r.w = hi.y;
    return r;
}

typedef const __attribute__((address_space(1))) void* gas_t;
typedef __attribute__((address_space(3))) void* las_t;
static __device__ __forceinline__ void gld16(const void* g, void* l) {
    __builtin_amdgcn_global_load_lds((gas_t)g, (las_t)l, 16, 0, 0);
}

// exact fp32 dot over 768 elems, whole wave participates; all lanes return sum
static __device__ __forceinline__ float wave_dot(const float* __restrict__ a,
                                                 const float* __restrict__ b,
                                                 int lane) {
    f32x4 s4 = {0.f, 0.f, 0.f, 0.f};
#pragma unroll
    for (int it = 0; it < 3; ++it) {
        int k = it * 256 + lane * 4;
        f32x4 av = *(const f32x4*)(a + k);
        f32x4 bv = *(const f32x4*)(b + k);
#pragma unroll
        for (int q = 0; q < 4; ++q) s4[q] = fmaf(av[q], bv[q], s4[q]);
    }
    float v = (s4[0] + s4[1]) + (s4[2] + s4[3]);
#pragma unroll
    for (int m = 1; m < 64; m <<= 1) v += __shfl_xor(v, m);
    return v;
}

// ---------------------------------------------------------------------------
// FUSED kernel (R10, verified best 303.8us): one block per pair, 512 threads
// / 8 waves. Phase 1: bf16-MFMA sim + top-2 margin + exact fp32 recheck,
// 1-deep prefetch, drain-every-step barriers (the tight schedule is what
// keeps the Cbf/Ebf write-back L3-hot for phase 2 — R13/R15 showed looser
// pipelines trade BW for L3-eviction traffic at a net loss).
// Phase 2: MLP GEMM over 3 column blocks from own cache-hot Cbf/Ebf + W1T.
// ---------------------------------------------------------------------------
__global__ __launch_bounds__(512, 4) void fused_kernel(
        const float* __restrict__ inp,
        const unsigned short* __restrict__ W1T,
        const float* __restrict__ b1,
        const float* __restrict__ W2,
        const float* __restrict__ b2,
        unsigned short* __restrict__ Cbf, unsigned short* __restrict__ Ebf,
        float* __restrict__ out)
{
    const int p    = blockIdx.x;
    const int t    = threadIdx.x;       // 0..511
    const int wv   = t >> 6;            // 0..7
    const int lane = t & 63;
    const int s    = lane & 15, g = lane >> 4;

    const float* Cbase = inp + (size_t)(2 * p) * LTOK * DDIM;
    const float* Ebase = Cbase + (size_t)LTOK * DDIM;

    __shared__ char  pool[49152];       // phase-overlapped
    __shared__ int   am[128];
    __shared__ float dm[128];
    __shared__ float tok[128];

    // phase-1 views of the pool
    unsigned short (*Cl)[128][32] = (unsigned short (*)[128][32])pool;
    unsigned short (*El)[128][32] = (unsigned short (*)[128][32])(pool + 16384);
    unsigned short (*cand)[16]    = (unsigned short (*)[16])(pool + 32768);
    int*   ccnt = (int*)(pool + 36864);
    float* rm1  = (float*)(pool + 37376);
    int*   ri1  = (int*)(pool + 37888);

    if (t < 128) { ccnt[t] = 0; tok[t] = 0.f; }

    // ================= Phase 1: sim + argmax =================
    f32x4 acc1[8];                       // rows wv*16+g*4+r, cols j*16+s
#pragma unroll
    for (int j = 0; j < 8; j++) acc1[j] = (f32x4){0.f, 0.f, 0.f, 0.f};

    const int srow0 = t >> 3;            // 0..63
    const int srow1 = 64 + srow0;        // 64..127
    const int so8   = t & 7;             // 8-elem chunk within 64-k
    const int sh    = so8 >> 2;          // k-half
    const int sq    = so8 & 3;           // logical 16B slot within half
    const int qs0   = (sq ^ fsw(srow0)) * 8;
    const int qs1   = (sq ^ fsw(srow1)) * 8;

    f32x4 cbuf[4], ebuf[4];

    auto ISSUE = [&](int kc) {
        const int k0 = kc * 64;
        const float* c0a = Cbase + (size_t)srow0 * DDIM + k0 + so8 * 8;
        const float* c1a = Cbase + (size_t)srow1 * DDIM + k0 + so8 * 8;
        const float* e0a = Ebase + (size_t)srow0 * DDIM + k0 + so8 * 8;
        const float* e1a = Ebase + (size_t)srow1 * DDIM + k0 + so8 * 8;
        cbuf[0] = *(const f32x4*)c0a;  cbuf[1] = *(const f32x4*)(c0a + 4);
        cbuf[2] = *(const f32x4*)c1a;  cbuf[3] = *(const f32x4*)(c1a + 4);
        ebuf[0] = *(const f32x4*)e0a;  ebuf[1] = *(const f32x4*)(e0a + 4);
        ebuf[2] = *(const f32x4*)e1a;  ebuf[3] = *(const f32x4*)(e1a + 4);
    };

    ISSUE(0);
    for (int kc = 0; kc < 12; ++kc) {
        const int k0 = kc * 64;
        uint4 cw0 = pack8(cbuf[0], cbuf[1]);
        uint4 cw1 = pack8(cbuf[2], cbuf[3]);
        uint4 ew0 = pack8(ebuf[0], ebuf[1]);
        uint4 ew1 = pack8(ebuf[2], ebuf[3]);
        *(uint4*)&Cl[sh][srow0][qs0] = cw0;
        *(uint4*)&Cl[sh][srow1][qs1] = cw1;
        *(uint4*)&El[sh][srow0][qs0] = ew0;
        *(uint4*)&El[sh][srow1][qs1] = ew1;
        __syncthreads();                        // A: LDS tiles visible

        if (kc < 11) ISSUE(kc + 1);             // prefetch flies under MFMA
        {                                       // WB (linear) acks under MFMA
            size_t o0 = ((size_t)p * LTOK + srow0) * DDIM + k0 + so8 * 8;
            size_t o1 = ((size_t)p * LTOK + srow1) * DDIM + k0 + so8 * 8;
            *(uint4*)(Cbf + o0) = cw0;
            *(uint4*)(Cbf + o1) = cw1;
            *(uint4*)(Ebf + o0) = ew0;
            *(uint4*)(Ebf + o1) = ew1;
        }

#pragma unroll
        for (int hh = 0; hh < 2; ++hh) {
            const int arow = wv * 16 + s;
            bf16x8 af = *(const bf16x8*)&Cl[hh][arow][(g ^ fsw(arow)) * 8];
            bf16x8 bfr[8];
#pragma unroll
            for (int j = 0; j < 8; ++j) {
                const int row = j * 16 + s;
                bfr[j] = *(const bf16x8*)&El[hh][row][(g ^ fsw(row)) * 8];
            }
#pragma unroll
            for (int j = 0; j < 8; ++j)
                acc1[j] = __builtin_amdgcn_mfma_f32_16x16x32_bf16(af, bfr[j], acc1[j], 0, 0, 0);
        }
        __syncthreads();                        // B: loads+stores drained
    }

    // top-2 per row; row = wv*16 + g*4 + r
#pragma unroll
    for (int r = 0; r < 4; ++r) {
        float m1 = acc1[0][r]; int i1 = s; float m2 = -1e30f;
#pragma unroll
        for (int j = 1; j < 8; ++j) {
            float v = acc1[j][r]; int c = j * 16 + s;
            if (v > m1 || (v == m1 && c < i1)) { m2 = m1; m1 = v; i1 = c; }
            else if (v > m2) m2 = v;
        }
#pragma unroll
        for (int msk = 1; msk < 16; msk <<= 1) {
            float o1 = __shfl_xor(m1, msk);
            int   oi = __shfl_xor(i1, msk);
            float o2 = __shfl_xor(m2, msk);
            bool take = (o1 > m1) || (o1 == m1 && oi < i1);
            float nm2 = take ? fmaxf(m1, o2) : fmaxf(m2, o1);
            if (take) { m1 = o1; i1 = oi; }
            m2 = nm2;
        }
        int row = wv * 16 + g * 4 + r;
        if (s == 0) { rm1[row] = m1; ri1[row] = i1; }
        float thr = m1 - MARGIN;
#pragma unroll
        for (int j = 0; j < 8; ++j) {
            float v = acc1[j][r]; int c = j * 16 + s;
            if (v >= thr && c != i1) {
                int idx = atomicAdd(&ccnt[row], 1);
                if (idx < 16) cand[row][idx] = (unsigned short)c;
            }
        }
    }
    __syncthreads();

    // phase B: per row, commit bf16 result or exact-fp32 recheck -> am/dm LDS
    for (int rr = 0; rr < 16; ++rr) {
        int row = wv + rr * 8;
        int cnt = ccnt[row];
        float m1 = rm1[row]; int i1 = ri1[row];
        if (cnt == 0) {
            if (lane == 0) { dm[row] = m1; am[row] = i1; }
            continue;
        }
        const float* cr = Cbase + (size_t)row * DDIM;
        float bv; int bc;
        if (cnt <= 16) {
            bv = wave_dot(cr, Ebase + (size_t)i1 * DDIM, lane); bc = i1;
            for (int q = 0; q < cnt; ++q) {
                int c = cand[row][q];
                float v = wave_dot(cr, Ebase + (size_t)c * DDIM, lane);
                if (v > bv || (v == bv && c < bc)) { bv = v; bc = c; }
            }
        } else {
            bv = -1e30f; bc = 0;
            for (int c = 0; c < 128; ++c) {
                float v = wave_dot(cr, Ebase + (size_t)c * DDIM, lane);
                if (v > bv || (v == bv && c < bc)) { bv = v; bc = c; }
            }
        }
        if (lane == 0) { dm[row] = bv; am[row] = bc; }
    }
    __syncthreads();    // am/dm ready; phase-1 pool dead -> reuse

    // ================= Phase 2: MLP GEMM =================
    unsigned short (*Ald)[128][32] = (unsigned short (*)[128][32])pool;
    unsigned short (*Bld)[256][32] = (unsigned short (*)[256][32])(pool + 16384);

    const int wr  = wv >> 2, wcg = wv & 3;  // 2x4 wave grid: 64 rows x 64 cols
    const int rsub = lane >> 2;             // 0..15
    const int chk  = lane & 3;              // 16B chunk

    for (int cb = 0; cb < 3; ++cb) {
        f32x4 acc[4][4];
#pragma unroll
        for (int i = 0; i < 4; i++)
#pragma unroll
            for (int j = 0; j < 4; j++) acc[i][j] = (f32x4){0.f, 0.f, 0.f, 0.f};

        auto STAGE = [&](int buf, int kt) {
            const int k0   = kt * 32;
            const bool ctx = (kt < 24);
            const int kloc = ctx ? k0 : (k0 - DDIM);
            // B: 2 gld16 per wave (16 cols x 64B each)
#pragma unroll
            for (int n = 0; n < 2; ++n) {
                int r0  = (wv * 2 + n) * 16;
                int col = r0 + rsub;                  // 0..255
                int ck  = chk ^ fsw(col);             // pre-swizzled source chunk
                gld16(W1T + (size_t)(cb * 256 + col) * K2 + k0 + ck * 8,
                      &Bld[buf][r0][0]);
            }
            // A: 1 gld16 per wave (16 rows x 64B)
            {
                int r0 = wv * 16;
                int r  = r0 + rsub;
                int ck = chk ^ fsw(r);
                const unsigned short* base = ctx
                    ? (Cbf + ((size_t)p * LTOK + r) * DDIM)
                    : (Ebf + ((size_t)p * LTOK + am[r]) * DDIM);
                gld16(base + kloc + ck * 8, &Ald[buf][r0][0]);
            }
        };

        STAGE(0, 0);
        __syncthreads();
        int cur = 0;
        for (int kt = 0; kt < 48; ++kt) {
            if (kt < 47) STAGE(cur ^ 1, kt + 1);   // next tile flies under MFMA
            bf16x8 af[4], bfr[4];
#pragma unroll
            for (int i = 0; i < 4; ++i) {
                const int row = wr * 64 + i * 16 + s;
                af[i] = *(const bf16x8*)&Ald[cur][row][(g ^ fsw(row)) * 8];
            }
#pragma unroll
            for (int j = 0; j < 4; ++j) {
                const int brow = wcg * 64 + j * 16 + s;
                bfr[j] = *(const bf16x8*)&Bld[cur][brow][(g ^ fsw(brow)) * 8];
            }
#pragma unroll
            for (int i = 0; i < 4; ++i)
#pragma unroll
                for (int j = 0; j < 4; ++j)
                    acc[i][j] = __builtin_amdgcn_mfma_f32_16x16x32_bf16(af[i], bfr[j], acc[i][j], 0, 0, 0);
            __syncthreads();
            cur ^= 1;
        }

        // epilogue: relu(acc + b1) . W2, reduce cols, accumulate LDS tok
        float w2v[4], b1v[4];
#pragma unroll
        for (int j = 0; j < 4; j++) {
            int col = cb * 256 + wcg * 64 + j * 16 + s;
            w2v[j] = W2[col];
            b1v[j] = b1[col];
        }
        float ss[4][4];
#pragma unroll
        for (int i = 0; i < 4; i++)
#pragma unroll
            for (int r = 0; r < 4; r++) ss[i][r] = 0.f;
#pragma unroll
        for (int i = 0; i < 4; i++)
#pragma unroll
            for (int j = 0; j < 4; j++)
#pragma unroll
                for (int r = 0; r < 4; r++) {
                    float h = acc[i][j][r] + b1v[j];
                    h = h > 0.f ? h : 0.f;
                    ss[i][r] = fmaf(h, w2v[j], ss[i][r]);
                }
#pragma unroll
        for (int sft = 1; sft < 16; sft <<= 1)
#pragma unroll
            for (int i = 0; i < 4; i++)
#pragma unroll
                for (int r = 0; r < 4; r++) ss[i][r] += __shfl_xor(ss[i][r], sft);
        if (s == 0) {
#pragma unroll
            for (int i = 0; i < 4; i++)
#pragma unroll
                for (int r = 0; r < 4; r++)
                    atomicAdd(&tok[wr * 64 + i * 16 + g * 4 + r], ss[i][r]);
        }
    }
    __syncthreads();

    // final: masked row sums -> out[p] (scores), out[512+p] (dot_scores)
    if (wv == 0) {
        float b2v = b2[0];
        float sc = 0.f, dd = 0.f;
#pragma unroll
        for (int rr = 0; rr < 2; ++rr) {
            int row = lane + rr * 64;
            float c0 = Cbase[(size_t)row * DDIM];
            float mk = (c0 != 0.f) ? 1.f : 0.f;
            sc += mk * (tok[row] + b2v);
            dd += mk * dm[row];
        }
#pragma unroll
        for (int m = 1; m < 64; m <<= 1) {
            sc += __shfl_xor(sc, m);
            dd += __shfl_xor(dd, m);
        }
        if (lane == 0) { out[p] = sc; out[NPAIR + p] = dd; }
    }
}

// ---------------------------------------------------------------------------
// Kernel 2: W1 [1536,768] fp32 -> W1T [768][1536] bf16 (coalesced writes)
// ---------------------------------------------------------------------------
__global__ __launch_bounds__(256) void w1t_kernel(
        const float* __restrict__ W1, unsigned short* __restrict__ W1T)
{
    int idx = blockIdx.x * 256 + threadIdx.x;
    if (idx >= HDIM * K2 / 8) return;
    int c  = idx / (K2 / 8);
    int k0 = (idx % (K2 / 8)) * 8;
    unsigned short v[8];
#pragma unroll
    for (int q = 0; q < 8; q++) v[q] = f2bf(W1[(size_t)(k0 + q) * HDIM + c]);
    *(uint4*)(W1T + (size_t)c * K2 + k0) = *(const uint4*)v;
}

// ---------------------------------------------------------------------------
// Fallback kernels (ws too small): fp32 sim + fused-gather MLP + atomics
// ---------------------------------------------------------------------------
__global__ __launch_bounds__(256) void sim_fp32_kernel(
        const float* __restrict__ inp,
        float* __restrict__ dotmax, int* __restrict__ argmax)
{
    const int p  = blockIdx.x;
    const int t  = threadIdx.x;
    const int tx = t & 15, ty = t >> 4;
    const float* Cbase = inp + (size_t)(2 * p) * LTOK * DDIM;
    const float* Ebase = Cbase + (size_t)LTOK * DDIM;

    __shared__ float Ct[128][36];
    __shared__ float Et[128][36];

    float acc[8][8];
#pragma unroll
    for (int i = 0; i < 8; i++)
#pragma unroll
        for (int j = 0; j < 8; j++) acc[i][j] = 0.f;

    for (int kc = 0; kc < 24; ++kc) {
        const int k0 = kc * 32;
#pragma unroll
        for (int q = 0; q < 4; ++q) {
            int f = q * 256 + t;
            int row = f >> 3, c4 = f & 7;
            *(f32x4*)&Ct[row][c4 * 4] = *(const f32x4*)(Cbase + (size_t)row * DDIM + k0 + c4 * 4);
            *(f32x4*)&Et[row][c4 * 4] = *(const f32x4*)(Ebase + (size_t)row * DDIM + k0 + c4 * 4);
        }
        __syncthreads();
#pragma unroll
        for (int kk4 = 0; kk4 < 8; ++kk4) {
            f32x4 cr[8], er[8];
#pragma unroll
            for (int i = 0; i < 8; i++) cr[i] = *(const f32x4*)&Ct[ty + 16 * i][kk4 * 4];
#pragma unroll
            for (int j = 0; j < 8; j++) er[j] = *(const f32x4*)&Et[tx + 16 * j][kk4 * 4];
#pragma unroll
            for (int kk = 0; kk < 4; kk++)
#pragma unroll
                for (int i = 0; i < 8; i++)
#pragma unroll
                    for (int j = 0; j < 8; j++)
                        acc[i][j] = fmaf(cr[i][kk], er[j][kk], acc[i][j]);
        }
        __syncthreads();
    }
#pragma unroll
    for (int i = 0; i < 8; i++) {
        float m = acc[i][0]; int mi = tx;
#pragma unroll
        for (int j = 1; j < 8; j++) {
            int c = tx + 16 * j;
            float v = acc[i][j];
            if (v > m || (v == m && c < mi)) { m = v; mi = c; }
        }
#pragma unroll
        for (int sft = 1; sft < 16; sft <<= 1) {
            float vo = __shfl_xor(m, sft);
            int   io = __shfl_xor(mi, sft);
            if (vo > m || (vo == m && io < mi)) { m = vo; mi = io; }
        }
        if (tx == 0) {
            int r = ty + 16 * i;
            dotmax[(size_t)p * LTOK + r] = m;
            argmax[(size_t)p * LTOK + r] = mi;
        }
    }
}

__global__ __launch_bounds__(256, 2) void mlp_kernel(
        const float* __restrict__ inp,
        const unsigned short* __restrict__ W1T,
        const float* __restrict__ b1,
        const float* __restrict__ W2,
        const int* __restrict__ argmax,
        float* __restrict__ tokscore)
{
    const int tile = blockIdx.x;
    const int cb   = blockIdx.y;
    const int t    = threadIdx.x;
    const int wv   = t >> 6;
    const int lane = t & 63;
    const int s    = lane & 15, g = lane >> 4;

    __shared__ unsigned short At[64][32];
    __shared__ unsigned short Bt[384][32];
    __shared__ int am[64];

    if (t < 64) am[t] = argmax[tile * 64 + t];
    __syncthreads();

    f32x4 acc[4][6];
#pragma unroll
    for (int i = 0; i < 4; i++)
#pragma unroll
        for (int j = 0; j < 6; j++) acc[i][j] = (f32x4){0.f, 0.f, 0.f, 0.f};

    for (int kc = 0; kc < 48; ++kc) {
        const int k0  = kc * 32;
        const int sel = (kc >= 24) ? 1 : 0;
        const int kloc = k0 - sel * DDIM;
#pragma unroll
        for (int q = 0; q < 2; ++q) {
            int f = q * 256 + t;
            int row = f >> 3, c4 = f & 7;
            int token = tile * 64 + row;
            int pp2 = token >> 7;
            int lsel = sel ? am[row] : (token & 127);
            const float* src = inp + ((size_t)(2 * pp2 + sel) * LTOK + lsel) * DDIM + kloc + c4 * 4;
            f32x4 v = *(const f32x4*)src;
            uint2 pk = pack4(v);
            *(uint2*)&At[row][c4 * 4] = pk;
        }
#pragma unroll
        for (int q = 0; q < 6; ++q) {
            int f = q * 256 + t;
            int colr = f >> 2, q8 = f & 3;
            const unsigned short* src = W1T + (size_t)(cb * 384 + colr) * K2 + k0 + q8 * 8;
            *(uint4*)&Bt[colr][q8 * 8] = *(const uint4*)src;
        }
        __syncthreads();

        bf16x8 af[4], bfr[6];
#pragma unroll
        for (int i = 0; i < 4; i++) af[i]  = *(const bf16x8*)&At[i * 16 + s][g * 8];
#pragma unroll
        for (int j = 0; j < 6; j++) bfr[j] = *(const bf16x8*)&Bt[wv * 96 + j * 16 + s][g * 8];
#pragma unroll
        for (int i = 0; i < 4; i++)
#pragma unroll
            for (int j = 0; j < 6; j++)
                acc[i][j] = __builtin_amdgcn_mfma_f32_16x16x32_bf16(af[i], bfr[j], acc[i][j], 0, 0, 0);
        __syncthreads();
    }

    float w2v[6], b1v[6];
#pragma unroll
    for (int j = 0; j < 6; j++) {
        int col = cb * 384 + wv * 96 + j * 16 + s;
        w2v[j] = W2[col];
        b1v[j] = b1[col];
    }
    float ssum[4][4];
#pragma unroll
    for (int i = 0; i < 4; i++)
#pragma unroll
        for (int r = 0; r < 4; r++) ssum[i][r] = 0.f;
#pragma unroll
    for (int i = 0; i < 4; i++)
#pragma unroll
        for (int j = 0; j < 6; j++)
#pragma unroll
            for (int r = 0; r < 4; r++) {
                float hh = acc[i][j][r] + b1v[j];
                hh = hh > 0.f ? hh : 0.f;
                ssum[i][r] = fmaf(hh, w2v[j], ssum[i][r]);
            }
#pragma unroll
    for (int sft = 1; sft < 16; sft <<= 1)
#pragma unroll
        for (int i = 0; i < 4; i++)
#pragma unroll
            for (int r = 0; r < 4; r++) ssum[i][r] += __shfl_xor(ssum[i][r], sft);
    if (s == 0) {
#pragma unroll
        for (int i = 0; i < 4; i++)
#pragma unroll
            for (int r = 0; r < 4; r++)
                atomicAdd(&tokscore[tile * 64 + i * 16 + g * 4 + r], ssum[i][r]);
    }
}

__global__ __launch_bounds__(128) void reduce_kernel(
        const float* __restrict__ inp,
        const float* __restrict__ tokscore,
        const float* __restrict__ dotmax,
        const float* __restrict__ b2,
        float* __restrict__ out)
{
    int p = blockIdx.x;
    int l = threadIdx.x;
    float c0  = inp[((size_t)(2 * p) * LTOK + l) * DDIM];
    float msk = (c0 != 0.0f) ? 1.f : 0.f;
    float sc  = (tokscore[p * LTOK + l] + b2[0]) * msk;
    float dmv = dotmax[p * LTOK + l] * msk;
#pragma unroll
    for (int sh = 1; sh < 64; sh <<= 1) {
        sc  += __shfl_xor(sc, sh);
        dmv += __shfl_xor(dmv, sh);
    }
    __shared__ float tmp[4];
    if ((l & 63) == 0) { tmp[(l >> 6) * 2] = sc; tmp[(l >> 6) * 2 + 1] = dmv; }
    __syncthreads();
    if (l == 0) {
        out[p]          = tmp[0] + tmp[2];
        out[NPAIR + p]  = tmp[1] + tmp[3];
    }
}

extern "C" void kernel_launch(void* const* d_in, const int* in_sizes, int n_in,
                              void* d_out, int out_size, void* d_ws, size_t ws_size,
                              hipStream_t stream)
{
    const float* inp = (const float*)d_in[0];
    const float* W1  = (const float*)d_in[1];
    const float* b1  = (const float*)d_in[2];
    const float* W2  = (const float*)d_in[3];
    const float* b2  = (const float*)d_in[4];
    float* out = (float*)d_out;

    char* ws = (char*)d_ws;
    unsigned short* W1T   = (unsigned short*)ws;                 // 2,359,296 B
    float*          dotmx = (float*)(ws + 2359296);              // fallback
    int*            amax  = (int*)(ws + 2359296 + 262144);       // fallback
    float*          toksc = (float*)(ws + 2359296 + 2*262144);   // fallback
    unsigned short* Cbf   = (unsigned short*)(ws + 2359296 + 3*262144);
    unsigned short* Ebf   = Cbf + (size_t)NPAIR * LTOK * DDIM;   // +100,663,296 B each
    const size_t NEED = 2359296ull + 3ull*262144ull + 2ull*100663296ull;

    const bool big = ws_size >= NEED;

    w1t_kernel<<<(HDIM * K2 / 8 + 255) / 256, 256, 0, stream>>>(W1, W1T);
    if (big) {
        fused_kernel<<<NPAIR, 512, 0, stream>>>(inp, W1T, b1, W2, b2, Cbf, Ebf, out);
    } else {
        hipMemsetAsync(toksc, 0, 65536 * sizeof(float), stream);
        sim_fp32_kernel<<<NPAIR, 256, 0, stream>>>(inp, dotmx, amax);
        mlp_kernel<<<dim3(1024, 2), 256, 0, stream>>>(inp, W1T, b1, W2, amax, toksc);
        reduce_kernel<<<NPAIR, 128, 0, stream>>>(inp, toksc, dotmx, b2, out);
    }
}